// Round 17
// baseline (319.975 us; speedup 1.0000x reference)
//
#include <hip/hip_runtime.h>
#include <hip/hip_fp16.h>
#include <math.h>

#define NNODES 50000
#define NEDGES 500000
#define HID 128
#define NCLS 40

using half8v = __attribute__((ext_vector_type(8))) _Float16;
using float4v = __attribute__((ext_vector_type(4))) float;
using uint4v = __attribute__((ext_vector_type(4))) unsigned;

static __device__ __forceinline__ unsigned h2u(__half2 h) {
    union { __half2 h; unsigned u; } x; x.h = h; return x.u;
}
static __device__ __forceinline__ __half2 u2h(unsigned u) {
    union { unsigned u; __half2 h; } x; x.u = u; return x.h;
}

// ---------------------------------------------------------------------------
// prep_edges: rowptrs for A/B + interleaved {col, val-as-half2} streams
// ---------------------------------------------------------------------------
static __device__ __forceinline__ void rowptr_body(const int* __restrict__ row,
                                                   int e, int* __restrict__ rp) {
    if (e >= NEDGES) return;
    int r = row[e];
    int prev = (e == 0) ? -1 : row[e - 1];
    for (int q = prev + 1; q <= r; ++q) rp[q] = e;
    if (e == NEDGES - 1) {
        for (int q = r + 1; q <= NNODES; ++q) rp[q] = NEDGES;
    }
}

static __global__ void prep_edges_kernel(const int* __restrict__ arow,
                                         const int* __restrict__ acol,
                                         const float* __restrict__ aval,
                                         const int* __restrict__ brow,
                                         const int* __restrict__ bcol,
                                         const float* __restrict__ bval,
                                         const int* __restrict__ id,
                                         int* __restrict__ rpa, int* __restrict__ rpb,
                                         int2* __restrict__ cvA, int2* __restrict__ cvB,
                                         int gE) {
    int bid = blockIdx.x;
    if (bid < gE) {
        rowptr_body(arow, bid * 256 + threadIdx.x, rpa);
    } else if (bid < 2 * gE) {
        rowptr_body(brow, (bid - gE) * 256 + threadIdx.x, rpb);
    } else if (bid < 3 * gE) {
        int e = (bid - 2 * gE) * 256 + threadIdx.x;
        if (e < NEDGES) {
            __half2 v = __float2half2_rn(aval[e]);
            cvA[e] = make_int2(acol[e], (int)h2u(v));
        }
    } else {
        int e = (bid - 3 * gE) * 256 + threadIdx.x;
        if (e < NEDGES) {
            __half2 v = __float2half2_rn(bval[e]);
            cvB[e] = make_int2(id[bcol[e]], (int)h2u(v));
        }
    }
}

// ---------------------------------------------------------------------------
// prep_x: x0h = f16(x0); xmh = f16(r*x0 + (1-r)*x0[id])
// ---------------------------------------------------------------------------
static __global__ void prep_x_kernel(const float4* __restrict__ x, const int* __restrict__ id,
                                     const float* __restrict__ mixr,
                                     uint2* __restrict__ x0h, uint2* xmh) {
    int i = blockIdx.x * blockDim.x + threadIdx.x;   // exactly N*HID/4
    int n = i >> 5, qq = i & 31;
    float r = mixr[0];
    float4 a = x[i];
    float4 b = x[(size_t)id[n] * 32 + qq];
    uint2 pa, pm;
    pa.x = h2u(__floats2half2_rn(a.x, a.y));
    pa.y = h2u(__floats2half2_rn(a.z, a.w));
    pm.x = h2u(__floats2half2_rn(r * a.x + (1.f - r) * b.x, r * a.y + (1.f - r) * b.y));
    pm.y = h2u(__floats2half2_rn(r * a.z + (1.f - r) * b.z, r * a.w + (1.f - r) * b.w));
    x0h[i] = pa;
    xmh[i] = pm;
}

// ---------------------------------------------------------------------------
// prep_w: Wt[mat][n][k] f16 for 6 mats (0-2 Wl, 3-5 Wr), then WoT[c][k] 48-pad
// ---------------------------------------------------------------------------
static __global__ void prep_w_kernel(const float* __restrict__ Wl, const float* __restrict__ Wr,
                                     const float* __restrict__ Wout,
                                     __half* __restrict__ Wt, __half* __restrict__ WoT) {
    int t = blockIdx.x * blockDim.x + threadIdx.x;   // exactly 6*16384 + 48*128
    if (t < 6 * 16384) {
        int mat = t >> 14, idx = t & 16383;
        int n = idx >> 7, k = idx & 127;
        const float* src = (mat < 3) ? (Wl + mat * 16384) : (Wr + (mat - 3) * 16384);
        Wt[t] = __float2half(src[k * HID + n]);
    } else {
        int u = t - 6 * 16384;
        int c = u >> 7, k = u & 127;
        WoT[u] = (c < NCLS) ? __float2half(Wout[k * NCLS + c]) : __float2half(0.f);
    }
}

// ---------------------------------------------------------------------------
// MFMA helpers: swapped-operand f16 layout
//   D[row = lane&15][col = tile*16 + (lane>>4)*4 + i]
// ---------------------------------------------------------------------------
#define LOAD_H4(ptr, w0, w1, w2, w3)                                            \
    w0 = *(const half8v*)(ptr);                                                 \
    w1 = *(const half8v*)((ptr) + 32);                                          \
    w2 = *(const half8v*)((ptr) + 64);                                          \
    w3 = *(const half8v*)((ptr) + 96);

#define MFMA4(w0, w1, w2, w3, x0, x1, x2, x3, t)                                \
    t = __builtin_amdgcn_mfma_f32_16x16x32_f16(w0, x0, t, 0, 0, 0);             \
    t = __builtin_amdgcn_mfma_f32_16x16x32_f16(w1, x1, t, 0, 0, 0);             \
    t = __builtin_amdgcn_mfma_f32_16x16x32_f16(w2, x2, t, 0, 0, 0);             \
    t = __builtin_amdgcn_mfma_f32_16x16x32_f16(w3, x3, t, 0, 0, 0);

// ---------------------------------------------------------------------------
// layer_kernel<DO_HY>: merged SpMM-gather + SAGE layer. 256 thr / 64 nodes.
// Phase 1: quarter-wave qw dual-stream-gathers nodes qw*4+k (k=0..3) from
//          src (f16 rows, 16 lanes x 16B), A+B streams simultaneously with
//          cv 1-ahead prefetch, f16 hfma2 -> Sls/Tls (LDS only, no HBM trip).
// Phase 2: barrier; A-frags from LDS; per col-tile c: block stages Wl/Wr
//          tile into double-buffered LDS, MFMA:
//            S = Sh@Wl; T = Th@Wl; z = xm@Wr + b; DO_HY: hz = src@Wr
//            h' = relu(S + hz + b); xm' = r*relu(S+z) + (1-r)*relu(T+z)
//          !DO_HY: xm' -> hs (aliases Sls; S-frags already in regs);
//                  head: logits = xm'@WoT + bout; log_softmax -> out
// ---------------------------------------------------------------------------
template <bool DO_HY>
static __global__ __launch_bounds__(256, 3) void layer_kernel(
    const __half* __restrict__ src,
    const int2* __restrict__ cvA, const int* __restrict__ rpA,
    const int2* __restrict__ cvB, const int* __restrict__ rpB,
    __half* xm,
    const __half* __restrict__ Wl, const __half* __restrict__ Wr,
    const float* __restrict__ bias, const float* __restrict__ mixr,
    __half* __restrict__ hOut,
    const __half* __restrict__ WoT, const float* __restrict__ bout,
    float* __restrict__ out) {
    __shared__ __align__(16) _Float16 Sls[64][136];
    __shared__ __align__(16) _Float16 Tls[64][136];
    __shared__ __align__(16) _Float16 Wls[2][16][136];
    __shared__ __align__(16) _Float16 Wrs[2][16][136];
    const int tid = threadIdx.x;
    const int lr = tid & 15;
    const int lg = (tid >> 4) & 3;
    const int wv = tid >> 6;
    const int gr0 = blockIdx.x * 64;
    const int row = gr0 + wv * 16 + lr;
    const int rowc = min(row, NNODES - 1);
    const size_t rbase = (size_t)rowc * HID;
    const float rr = mixr[0];
    const int srow = tid >> 4, scol = (tid & 15) * 8;

    // ---- phase-2 operands issued first (fly under the gather)
    half8v xm0, xm1, xm2, xm3, hh0, hh1, hh2, hh3;
    {
        const __half* p = xm + rbase + lg * 8;
        LOAD_H4(p, xm0, xm1, xm2, xm3)
        if constexpr (DO_HY) {
            p = src + rbase + lg * 8;
            LOAD_H4(p, hh0, hh1, hh2, hh3)
        }
    }
    half8v wlreg = *(const half8v*)((const _Float16*)Wl + srow * HID + scol);
    half8v wrreg = *(const half8v*)((const _Float16*)Wr + srow * HID + scol);

    // ======== phase 1: dual-stream gather, 4 nodes per quarter-wave ========
    {
        const int qw = tid >> 4;
        const int j = tid & 15;
        const __half2 hz = __float2half2_rn(0.f);
#pragma unroll
        for (int k = 0; k < 4; ++k) {
            const int nl = qw * 4 + k;
            const int node = gr0 + nl;
            __half2 sa0 = hz, sa1 = hz, sa2 = hz, sa3 = hz;
            __half2 ta0 = hz, ta1 = hz, ta2 = hz, ta3 = hz;
            if (node < NNODES) {
                int eA = rpA[node];
                const int aE = rpA[node + 1];
                int eB = rpB[node];
                const int bE = rpB[node + 1];
                int2 mA = cvA[min(eA, NEDGES - 1)];
                int2 mB = cvB[min(eB, NEDGES - 1)];
                while (eA < aE || eB < bE) {
                    const bool vA = eA < aE, vB = eB < bE;
                    const int eA2 = eA + (vA ? 1 : 0);
                    const int eB2 = eB + (vB ? 1 : 0);
                    const int2 nA = cvA[min(eA2, NEDGES - 1)];
                    const int2 nB = cvB[min(eB2, NEDGES - 1)];
                    const uint4 pA = *(const uint4*)(src + (size_t)mA.x * HID + j * 8);
                    const uint4 pB = *(const uint4*)(src + (size_t)mB.x * HID + j * 8);
                    const __half2 vvA = vA ? u2h((unsigned)mA.y) : hz;
                    const __half2 vvB = vB ? u2h((unsigned)mB.y) : hz;
                    sa0 = __hfma2(u2h(pA.x), vvA, sa0); sa1 = __hfma2(u2h(pA.y), vvA, sa1);
                    sa2 = __hfma2(u2h(pA.z), vvA, sa2); sa3 = __hfma2(u2h(pA.w), vvA, sa3);
                    ta0 = __hfma2(u2h(pB.x), vvB, ta0); ta1 = __hfma2(u2h(pB.y), vvB, ta1);
                    ta2 = __hfma2(u2h(pB.z), vvB, ta2); ta3 = __hfma2(u2h(pB.w), vvB, ta3);
                    mA = nA; mB = nB; eA = eA2; eB = eB2;
                }
            }
            uint4v os, ot;
            os.x = h2u(sa0); os.y = h2u(sa1); os.z = h2u(sa2); os.w = h2u(sa3);
            ot.x = h2u(ta0); ot.y = h2u(ta1); ot.z = h2u(ta2); ot.w = h2u(ta3);
            *(uint4v*)&Sls[nl][j * 8] = os;
            *(uint4v*)&Tls[nl][j * 8] = ot;
        }
    }
    __syncthreads();

    // ======== phase 2: A-frags from LDS, LDS-W-staged MFMA ========
    half8v sh0, sh1, sh2, sh3, th0, th1, th2, th3;
    {
        const _Float16* sp = &Sls[wv * 16 + lr][lg * 8];
        LOAD_H4(sp, sh0, sh1, sh2, sh3)
        const _Float16* tp = &Tls[wv * 16 + lr][lg * 8];
        LOAD_H4(tp, th0, th1, th2, th3)
    }
    // hs aliases Sls (frags are in registers now; first write is after the
    // c-loop's first barrier, by which point all Sls reads have completed)
    _Float16 (*hs)[136] = Sls;

#pragma unroll
    for (int c = 0; c < 8; ++c) {
        const int buf = c & 1;
        *(half8v*)&Wls[buf][srow][scol] = wlreg;
        *(half8v*)&Wrs[buf][srow][scol] = wrreg;
        if (c < 7) {
            wlreg = *(const half8v*)((const _Float16*)Wl + (c + 1) * 2048 + srow * HID + scol);
            wrreg = *(const half8v*)((const _Float16*)Wr + (c + 1) * 2048 + srow * HID + scol);
        }
        __syncthreads();

        const _Float16* wlp = &Wls[buf][lr][lg * 8];
        const _Float16* wrp = &Wrs[buf][lr][lg * 8];
        half8v l0, l1, l2, l3, r0, r1, r2, r3;
        LOAD_H4(wlp, l0, l1, l2, l3)
        LOAD_H4(wrp, r0, r1, r2, r3)
        float4v aS = {0.f, 0.f, 0.f, 0.f}, aT = aS, aZ = aS, aH = aS;
        MFMA4(l0, l1, l2, l3, sh0, sh1, sh2, sh3, aS)
        MFMA4(l0, l1, l2, l3, th0, th1, th2, th3, aT)
        MFMA4(r0, r1, r2, r3, xm0, xm1, xm2, xm3, aZ)
        if constexpr (DO_HY) {
            MFMA4(r0, r1, r2, r3, hh0, hh1, hh2, hh3, aH)
        }
        const int col0 = c * 16 + lg * 4;
        const float4v bv = *(const float4v*)(bias + col0);
        __half xm4[4], h4[4];
#pragma unroll
        for (int i = 0; i < 4; ++i) {
            const float z = aZ[i] + bv[i];
            const float xa = fmaxf(aS[i] + z, 0.f);
            const float xb = fmaxf(aT[i] + z, 0.f);
            xm4[i] = __float2half(rr * xa + (1.f - rr) * xb);
            if constexpr (DO_HY) h4[i] = __float2half(fmaxf(aS[i] + aH[i] + bv[i], 0.f));
        }
        uint2 xmv;
        xmv.x = h2u(__half2{xm4[0], xm4[1]});
        xmv.y = h2u(__half2{xm4[2], xm4[3]});
        if constexpr (DO_HY) {
            uint2 hv;
            hv.x = h2u(__half2{h4[0], h4[1]});
            hv.y = h2u(__half2{h4[2], h4[3]});
            if (row < NNODES) {
                *(uint2*)(xm + rbase + col0) = xmv;
                *(uint2*)(hOut + rbase + col0) = hv;
            }
        } else {
            *(uint2*)((__half*)&hs[wv * 16 + lr][col0]) = xmv;
        }
        __syncthreads();   // all reads of buf done before iter c+2 overwrites
    }

    if constexpr (!DO_HY) {
        // head: logits = xm' @ WoT + bout; log_softmax per row
        const _Float16* lp = &hs[wv * 16 + lr][lg * 8];
        half8v c0, c1, c2, c3;
        LOAD_H4(lp, c0, c1, c2, c3)
        float lv[3][4];
        float mx = -INFINITY;
#pragma unroll
        for (int c = 0; c < 3; ++c) {
            const __half* wq = WoT + (size_t)(c * 16 + lr) * HID + lg * 8;
            half8v w0, w1, w2, w3;
            LOAD_H4(wq, w0, w1, w2, w3)
            float4v t = {0.f, 0.f, 0.f, 0.f};
            MFMA4(w0, w1, w2, w3, c0, c1, c2, c3, t)
            const int col0 = c * 16 + lg * 4;
            const bool valid = col0 < NCLS;
#pragma unroll
            for (int i = 0; i < 4; ++i) {
                const float l = valid ? (t[i] + bout[col0 + i]) : -INFINITY;
                lv[c][i] = l;
                mx = fmaxf(mx, l);
            }
        }
        mx = fmaxf(mx, __shfl_xor(mx, 16));
        mx = fmaxf(mx, __shfl_xor(mx, 32));
        float sum = 0.f;
#pragma unroll
        for (int c = 0; c < 3; ++c)
#pragma unroll
            for (int i = 0; i < 4; ++i)
                if (lv[c][i] > -INFINITY) sum += expf(lv[c][i] - mx);
        sum += __shfl_xor(sum, 16);
        sum += __shfl_xor(sum, 32);
        const float lse = mx + logf(sum);
#pragma unroll
        for (int c = 0; c < 3; ++c) {
            const int col0 = c * 16 + lg * 4;
            if (col0 < NCLS && row < NNODES) {
                float4 o = make_float4(lv[c][0] - lse, lv[c][1] - lse,
                                       lv[c][2] - lse, lv[c][3] - lse);
                *(float4*)(out + (size_t)row * NCLS + col0) = o;
            }
        }
    }
}

// ---------------------------------------------------------------------------
extern "C" void kernel_launch(void* const* d_in, const int* in_sizes, int n_in,
                              void* d_out, int out_size, void* d_ws, size_t ws_size,
                              hipStream_t stream) {
    const float* x0   = (const float*)d_in[0];
    const int*   arow = (const int*)d_in[1];
    const int*   acol = (const int*)d_in[2];
    const float* aval = (const float*)d_in[3];
    const int*   brow = (const int*)d_in[4];
    const int*   bcol = (const int*)d_in[5];
    const float* bval = (const float*)d_in[6];
    const float* mixr = (const float*)d_in[7];
    const int*   id   = (const int*)d_in[8];
    const float* Wl   = (const float*)d_in[9];
    const float* Wr   = (const float*)d_in[10];
    const float* bs   = (const float*)d_in[11];
    const float* Wout = (const float*)d_in[12];
    const float* bout = (const float*)d_in[13];
    float* out = (float*)d_out;

    const size_t NF = (size_t)NNODES * HID;   // 6.4M
    __half* x0h = (__half*)d_ws;
    __half* xmh = x0h + NF;
    __half* h1  = xmh + NF;
    __half* h2  = h1 + NF;
    __half* Wt  = h2 + NF;                    // 6 * 16384 f16
    __half* WoT = Wt + 6 * 16384;             // 48 * 128 f16
    int2* cvA = (int2*)(WoT + 48 * 128);      // E int2
    int2* cvB = cvA + NEDGES;
    int* rpa = (int*)(cvB + NEDGES);
    int* rpb = rpa + (NNODES + 1);

    const int gE = (NEDGES + 255) / 256;      // 1954
    const int gC = NNODES * HID / 4 / 256;    // 6250
    const int gG = (NNODES + 63) / 64;        // 782

    prep_edges_kernel<<<4 * gE, 256, 0, stream>>>(arow, acol, aval, brow, bcol, bval,
                                                  id, rpa, rpb, cvA, cvB, gE);
    prep_x_kernel<<<gC, 256, 0, stream>>>((const float4*)x0, id, mixr,
                                          (uint2*)x0h, (uint2*)xmh);
    prep_w_kernel<<<(6 * 16384 + 48 * 128) / 256, 256, 0, stream>>>(Wl, Wr, Wout, Wt, WoT);

    // ---- layer 0 (aggr source = x0)
    layer_kernel<true><<<gG, 256, 0, stream>>>(
        x0h, cvA, rpa, cvB, rpb, xmh,
        Wt + 0 * 16384, Wt + 3 * 16384, bs, mixr,
        h1, nullptr, nullptr, nullptr);

    // ---- layer 1 (aggr source = h1)
    layer_kernel<true><<<gG, 256, 0, stream>>>(
        h1, cvA, rpa, cvB, rpb, xmh,
        Wt + 1 * 16384, Wt + 4 * 16384, bs + 128, mixr,
        h2, nullptr, nullptr, nullptr);

    // ---- layer 2 (+ head, aggr source = h2)
    layer_kernel<false><<<gG, 256, 0, stream>>>(
        h2, cvA, rpa, cvB, rpb, xmh,
        Wt + 2 * 16384, Wt + 5 * 16384, bs + 256, mixr,
        nullptr, WoT, bout, out);
}

// Round 18
// 212.055 us; speedup vs baseline: 1.5089x; 1.5089x over previous
//
#include <hip/hip_runtime.h>
#include <hip/hip_fp16.h>
#include <math.h>

#define NNODES 50000
#define NEDGES 500000
#define HID 128
#define NCLS 40

using half8v = __attribute__((ext_vector_type(8))) _Float16;
using float4v = __attribute__((ext_vector_type(4))) float;
using uint4v = __attribute__((ext_vector_type(4))) unsigned;

static __device__ __forceinline__ unsigned h2u(__half2 h) {
    union { __half2 h; unsigned u; } x; x.h = h; return x.u;
}
static __device__ __forceinline__ __half2 u2h(unsigned u) {
    union { unsigned u; __half2 h; } x; x.u = u; return x.h;
}

// ---------------------------------------------------------------------------
// prep_all: one kernel, 6 block ranges:
//   [0,gE): rowptr A   [gE,2gE): rowptr B   [2gE,3gE): cvA   [3gE,4gE): cvB
//   [4gE,4gE+gC): x0h/xmh conversion        [4gE+gC,...): Wt/WoT conversion
// ---------------------------------------------------------------------------
static __device__ __forceinline__ void rowptr_body(const int* __restrict__ row,
                                                   int e, int* __restrict__ rp) {
    if (e >= NEDGES) return;
    int r = row[e];
    int prev = (e == 0) ? -1 : row[e - 1];
    for (int q = prev + 1; q <= r; ++q) rp[q] = e;
    if (e == NEDGES - 1) {
        for (int q = r + 1; q <= NNODES; ++q) rp[q] = NEDGES;
    }
}

static __global__ void prep_all_kernel(const int* __restrict__ arow,
                                       const int* __restrict__ acol,
                                       const float* __restrict__ aval,
                                       const int* __restrict__ brow,
                                       const int* __restrict__ bcol,
                                       const float* __restrict__ bval,
                                       const int* __restrict__ id,
                                       const float4* __restrict__ x,
                                       const float* __restrict__ mixr,
                                       const float* __restrict__ Wl,
                                       const float* __restrict__ Wr,
                                       const float* __restrict__ Wout,
                                       int* __restrict__ rpa, int* __restrict__ rpb,
                                       int2* __restrict__ cvA, int2* __restrict__ cvB,
                                       uint2* __restrict__ x0h, uint2* __restrict__ xmh,
                                       __half* __restrict__ Wt, __half* __restrict__ WoT,
                                       int gE, int gC) {
    int bid = blockIdx.x;
    if (bid < gE) {
        rowptr_body(arow, bid * 256 + threadIdx.x, rpa);
    } else if (bid < 2 * gE) {
        rowptr_body(brow, (bid - gE) * 256 + threadIdx.x, rpb);
    } else if (bid < 3 * gE) {
        int e = (bid - 2 * gE) * 256 + threadIdx.x;
        if (e < NEDGES) {
            __half2 v = __float2half2_rn(aval[e]);
            cvA[e] = make_int2(acol[e], (int)h2u(v));
        }
    } else if (bid < 4 * gE) {
        int e = (bid - 3 * gE) * 256 + threadIdx.x;
        if (e < NEDGES) {
            __half2 v = __float2half2_rn(bval[e]);
            cvB[e] = make_int2(id[bcol[e]], (int)h2u(v));
        }
    } else if (bid < 4 * gE + gC) {
        int i = (bid - 4 * gE) * 256 + threadIdx.x;   // exactly N*HID/4
        int n = i >> 5, qq = i & 31;
        float r = mixr[0];
        float4 a = x[i];
        float4 b = x[(size_t)id[n] * 32 + qq];
        uint2 pa, pm;
        pa.x = h2u(__floats2half2_rn(a.x, a.y));
        pa.y = h2u(__floats2half2_rn(a.z, a.w));
        pm.x = h2u(__floats2half2_rn(r * a.x + (1.f - r) * b.x, r * a.y + (1.f - r) * b.y));
        pm.y = h2u(__floats2half2_rn(r * a.z + (1.f - r) * b.z, r * a.w + (1.f - r) * b.w));
        x0h[i] = pa;
        xmh[i] = pm;
    } else {
        int t = (bid - 4 * gE - gC) * 256 + threadIdx.x;   // 6*16384 + 48*128
        if (t < 6 * 16384) {
            int mat = t >> 14, idx = t & 16383;
            int n = idx >> 7, k = idx & 127;
            const float* src = (mat < 3) ? (Wl + mat * 16384) : (Wr + (mat - 3) * 16384);
            Wt[t] = __float2half(src[k * HID + n]);
        } else if (t < 6 * 16384 + 48 * 128) {
            int u = t - 6 * 16384;
            int c = u >> 7, k = u & 127;
            WoT[u] = (c < NCLS) ? __float2half(Wout[k * NCLS + c]) : __float2half(0.f);
        }
    }
}

// ---------------------------------------------------------------------------
// spmm2: wave w<N -> Sh[w,:] via A edges; w>=N -> Th via B edges (f16 in/out).
// Quarter-wave (16 lanes x 16B) per row gather, cv prefetched 1-ahead,
// __hfma2 accumulate, non-temporal output stores.
// ---------------------------------------------------------------------------
static __global__ __launch_bounds__(256, 8) void spmm2_kernel(
    const __half* __restrict__ h,
    const int2* __restrict__ cvA, const int* __restrict__ rpA,
    __half* __restrict__ Sh,
    const int2* __restrict__ cvB, const int* __restrict__ rpB,
    __half* __restrict__ Th) {
    int w = blockIdx.x * 4 + (threadIdx.x >> 6);
    const int l = threadIdx.x & 63;
    const int q = l >> 4, j = l & 15;
    const int2* cv; const int* rp; __half* dst; int node;
    if (w < NNODES) { cv = cvA; rp = rpA; dst = Sh; node = w; }
    else            { cv = cvB; rp = rpB; dst = Th; node = w - NNODES; }
    const int e0 = rp[node], e1 = rp[node + 1];
    __half2 a0 = __float2half2_rn(0.f), a1 = a0, a2 = a0, a3 = a0;
    int e = e0 + q;
    int2 m0, m1;
    bool have = (e + 4 < e1);
    if (have) { m0 = cv[e]; m1 = cv[e + 4]; }
    while (have) {
        const int e2 = e + 8;
        const bool nxt = (e2 + 4 < e1);
        int2 k0 = m0, k1 = m1;
        if (nxt) { k0 = cv[e2]; k1 = cv[e2 + 4]; }
        const uint4 p0 = *(const uint4*)(h + (size_t)m0.x * HID + j * 8);
        const uint4 p1 = *(const uint4*)(h + (size_t)m1.x * HID + j * 8);
        const __half2 v0 = u2h((unsigned)m0.y), v1 = u2h((unsigned)m1.y);
        a0 = __hfma2(u2h(p0.x), v0, a0); a1 = __hfma2(u2h(p0.y), v0, a1);
        a2 = __hfma2(u2h(p0.z), v0, a2); a3 = __hfma2(u2h(p0.w), v0, a3);
        a0 = __hfma2(u2h(p1.x), v1, a0); a1 = __hfma2(u2h(p1.y), v1, a1);
        a2 = __hfma2(u2h(p1.z), v1, a2); a3 = __hfma2(u2h(p1.w), v1, a3);
        m0 = k0; m1 = k1; e = e2; have = nxt;
    }
    if (e < e1) {
        const int2 m = cv[e];
        const uint4 p = *(const uint4*)(h + (size_t)m.x * HID + j * 8);
        const __half2 v = u2h((unsigned)m.y);
        a0 = __hfma2(u2h(p.x), v, a0); a1 = __hfma2(u2h(p.y), v, a1);
        a2 = __hfma2(u2h(p.z), v, a2); a3 = __hfma2(u2h(p.w), v, a3);
    }
    a0 = __hadd2(a0, u2h(__shfl_xor((int)h2u(a0), 16)));
    a1 = __hadd2(a1, u2h(__shfl_xor((int)h2u(a1), 16)));
    a2 = __hadd2(a2, u2h(__shfl_xor((int)h2u(a2), 16)));
    a3 = __hadd2(a3, u2h(__shfl_xor((int)h2u(a3), 16)));
    a0 = __hadd2(a0, u2h(__shfl_xor((int)h2u(a0), 32)));
    a1 = __hadd2(a1, u2h(__shfl_xor((int)h2u(a1), 32)));
    a2 = __hadd2(a2, u2h(__shfl_xor((int)h2u(a2), 32)));
    a3 = __hadd2(a3, u2h(__shfl_xor((int)h2u(a3), 32)));
    if (l < 16) {
        uint4v o;
        o.x = h2u(a0); o.y = h2u(a1); o.z = h2u(a2); o.w = h2u(a3);
        __builtin_nontemporal_store(o, (uint4v*)(dst + (size_t)node * HID + l * 8));
    }
}

// ---------------------------------------------------------------------------
// Swapped-operand f16 MFMA: D[row = lane&15][col = tile*16 + (lane>>4)*4 + i]
// ---------------------------------------------------------------------------
#define LOAD_H4(ptr, w0, w1, w2, w3)                                            \
    w0 = *(const half8v*)(ptr);                                                 \
    w1 = *(const half8v*)((ptr) + 32);                                          \
    w2 = *(const half8v*)((ptr) + 64);                                          \
    w3 = *(const half8v*)((ptr) + 96);

#define LOAD_H4NT(ptr, w0, w1, w2, w3)                                          \
    w0 = __builtin_nontemporal_load((const half8v*)(ptr));                      \
    w1 = __builtin_nontemporal_load((const half8v*)((ptr) + 32));               \
    w2 = __builtin_nontemporal_load((const half8v*)((ptr) + 64));               \
    w3 = __builtin_nontemporal_load((const half8v*)((ptr) + 96));

#define MFMA4(w0, w1, w2, w3, x0, x1, x2, x3, t)                                \
    t = __builtin_amdgcn_mfma_f32_16x16x32_f16(w0, x0, t, 0, 0, 0);             \
    t = __builtin_amdgcn_mfma_f32_16x16x32_f16(w1, x1, t, 0, 0, 0);             \
    t = __builtin_amdgcn_mfma_f32_16x16x32_f16(w2, x2, t, 0, 0, 0);             \
    t = __builtin_amdgcn_mfma_f32_16x16x32_f16(w3, x3, t, 0, 0, 0);

// ---------------------------------------------------------------------------
// fused_layer<DO_HY>: 256 threads / 64 rows (4 waves x 16-row stripes).
// Per col-tile c: block stages Wl/Wr tile c (8 KB) into double-buffered LDS;
// global prefetch of tile c+1 issued before the barrier; waves MFMA their own
// A-fragments vs LDS W.
//   S = Sh@Wl; T = Th@Wl; z = xm@Wr + b; DO_HY: hz = hIn@Wr
//   h' = relu(S + hz + b);  xm' = r*relu(S+z) + (1-r)*relu(T+z)
//   !DO_HY: xm' -> hs LDS; head: logits = xm'@WoT + bout; log_softmax -> out
// ---------------------------------------------------------------------------
template <bool DO_HY>
static __global__ __launch_bounds__(256, 4) void fused_layer_kernel(
    const __half* __restrict__ Sh, const __half* __restrict__ Th,
    __half* xm, const __half* __restrict__ hIn,
    const __half* __restrict__ Wl, const __half* __restrict__ Wr,
    const float* __restrict__ bias, const float* __restrict__ mixr,
    __half* __restrict__ hOut,
    const __half* __restrict__ WoT, const float* __restrict__ bout,
    float* __restrict__ out) {
    __shared__ __align__(16) _Float16 Wls[2][16][136];
    __shared__ __align__(16) _Float16 Wrs[2][16][136];
    __shared__ __align__(16) __half hs[DO_HY ? 1 : 64][136];
    const int tid = threadIdx.x;
    const int lr = tid & 15;
    const int lg = (tid >> 4) & 3;
    const int wv = tid >> 6;
    const int row = blockIdx.x * 64 + wv * 16 + lr;
    const int rowc = min(row, NNODES - 1);
    const size_t rbase = (size_t)rowc * HID;
    const float rr = mixr[0];
    const int srow = tid >> 4, scol = (tid & 15) * 8;

    // ---- A-stream fragments (issued first; fly under the staging prologue)
    half8v sh0, sh1, sh2, sh3, th0, th1, th2, th3;
    half8v xm0, xm1, xm2, xm3, hh0, hh1, hh2, hh3;
    {
        const __half* p = Sh + rbase + lg * 8;
        LOAD_H4NT(p, sh0, sh1, sh2, sh3)
        p = Th + rbase + lg * 8;
        LOAD_H4NT(p, th0, th1, th2, th3)
        p = xm + rbase + lg * 8;
        LOAD_H4(p, xm0, xm1, xm2, xm3)
        if constexpr (DO_HY) {
            p = hIn + rbase + lg * 8;
            LOAD_H4(p, hh0, hh1, hh2, hh3)
        }
    }

    // ---- W staging prologue: tile 0 into registers
    half8v wlreg = *(const half8v*)((const _Float16*)Wl + srow * HID + scol);
    half8v wrreg = *(const half8v*)((const _Float16*)Wr + srow * HID + scol);

#pragma unroll
    for (int c = 0; c < 8; ++c) {
        const int buf = c & 1;
        *(half8v*)&Wls[buf][srow][scol] = wlreg;
        *(half8v*)&Wrs[buf][srow][scol] = wrreg;
        if (c < 7) {   // prefetch tile c+1 (flies during barrier + MFMA)
            wlreg = *(const half8v*)((const _Float16*)Wl + (c + 1) * 2048 + srow * HID + scol);
            wrreg = *(const half8v*)((const _Float16*)Wr + (c + 1) * 2048 + srow * HID + scol);
        }
        __syncthreads();

        const _Float16* wlp = &Wls[buf][lr][lg * 8];
        const _Float16* wrp = &Wrs[buf][lr][lg * 8];
        half8v l0, l1, l2, l3, r0, r1, r2, r3;
        LOAD_H4(wlp, l0, l1, l2, l3)
        LOAD_H4(wrp, r0, r1, r2, r3)
        float4v aS = {0.f, 0.f, 0.f, 0.f}, aT = aS, aZ = aS, aH = aS;
        MFMA4(l0, l1, l2, l3, sh0, sh1, sh2, sh3, aS)
        MFMA4(l0, l1, l2, l3, th0, th1, th2, th3, aT)
        MFMA4(r0, r1, r2, r3, xm0, xm1, xm2, xm3, aZ)
        if constexpr (DO_HY) {
            MFMA4(r0, r1, r2, r3, hh0, hh1, hh2, hh3, aH)
        }
        const int col0 = c * 16 + lg * 4;
        const float4v bv = *(const float4v*)(bias + col0);
        __half xm4[4], h4[4];
#pragma unroll
        for (int i = 0; i < 4; ++i) {
            const float z = aZ[i] + bv[i];
            const float xa = fmaxf(aS[i] + z, 0.f);
            const float xb = fmaxf(aT[i] + z, 0.f);
            xm4[i] = __float2half(rr * xa + (1.f - rr) * xb);
            if constexpr (DO_HY) h4[i] = __float2half(fmaxf(aS[i] + aH[i] + bv[i], 0.f));
        }
        uint2 xmv;
        xmv.x = h2u(__half2{xm4[0], xm4[1]});
        xmv.y = h2u(__half2{xm4[2], xm4[3]});
        if constexpr (DO_HY) {
            uint2 hv;
            hv.x = h2u(__half2{h4[0], h4[1]});
            hv.y = h2u(__half2{h4[2], h4[3]});
            if (row < NNODES) {
                *(uint2*)(xm + rbase + col0) = xmv;
                *(uint2*)(hOut + rbase + col0) = hv;
            }
        } else {
            *(uint2*)(&hs[wv * 16 + lr][col0]) = xmv;
        }
        __syncthreads();   // all reads of buf done before iter c+2 overwrites
    }

    if constexpr (!DO_HY) {
        // head: logits = xm' @ WoT + bout; log_softmax per row
        const __half* lp = &hs[wv * 16 + lr][lg * 8];
        half8v c0, c1, c2, c3;
        LOAD_H4(lp, c0, c1, c2, c3)
        float lv[3][4];
        float mx = -INFINITY;
#pragma unroll
        for (int c = 0; c < 3; ++c) {
            const __half* wq = WoT + (size_t)(c * 16 + lr) * HID + lg * 8;
            half8v w0, w1, w2, w3;
            LOAD_H4(wq, w0, w1, w2, w3)
            float4v t = {0.f, 0.f, 0.f, 0.f};
            MFMA4(w0, w1, w2, w3, c0, c1, c2, c3, t)
            const int col0 = c * 16 + lg * 4;
            const bool valid = col0 < NCLS;
#pragma unroll
            for (int i = 0; i < 4; ++i) {
                const float l = valid ? (t[i] + bout[col0 + i]) : -INFINITY;
                lv[c][i] = l;
                mx = fmaxf(mx, l);
            }
        }
        mx = fmaxf(mx, __shfl_xor(mx, 16));
        mx = fmaxf(mx, __shfl_xor(mx, 32));
        float sum = 0.f;
#pragma unroll
        for (int c = 0; c < 3; ++c)
#pragma unroll
            for (int i = 0; i < 4; ++i)
                if (lv[c][i] > -INFINITY) sum += expf(lv[c][i] - mx);
        sum += __shfl_xor(sum, 16);
        sum += __shfl_xor(sum, 32);
        const float lse = mx + logf(sum);
#pragma unroll
        for (int c = 0; c < 3; ++c) {
            const int col0 = c * 16 + lg * 4;
            if (col0 < NCLS && row < NNODES) {
                float4 o = make_float4(lv[c][0] - lse, lv[c][1] - lse,
                                       lv[c][2] - lse, lv[c][3] - lse);
                *(float4*)(out + (size_t)row * NCLS + col0) = o;
            }
        }
    }
}

// ---------------------------------------------------------------------------
extern "C" void kernel_launch(void* const* d_in, const int* in_sizes, int n_in,
                              void* d_out, int out_size, void* d_ws, size_t ws_size,
                              hipStream_t stream) {
    const float* x0   = (const float*)d_in[0];
    const int*   arow = (const int*)d_in[1];
    const int*   acol = (const int*)d_in[2];
    const float* aval = (const float*)d_in[3];
    const int*   brow = (const int*)d_in[4];
    const int*   bcol = (const int*)d_in[5];
    const float* bval = (const float*)d_in[6];
    const float* mixr = (const float*)d_in[7];
    const int*   id   = (const int*)d_in[8];
    const float* Wl   = (const float*)d_in[9];
    const float* Wr   = (const float*)d_in[10];
    const float* bs   = (const float*)d_in[11];
    const float* Wout = (const float*)d_in[12];
    const float* bout = (const float*)d_in[13];
    float* out = (float*)d_out;

    const size_t NF = (size_t)NNODES * HID;   // 6.4M
    __half* x0h = (__half*)d_ws;
    __half* xmh = x0h + NF;
    __half* h1  = xmh + NF;
    __half* h2  = h1 + NF;
    __half* Sh  = h2 + NF;
    __half* Th  = Sh + NF;
    __half* Wt  = Th + NF;                    // 6 * 16384 f16
    __half* WoT = Wt + 6 * 16384;             // 48 * 128 f16
    int2* cvA = (int2*)(WoT + 48 * 128);      // E int2
    int2* cvB = cvA + NEDGES;
    int* rpa = (int*)(cvB + NEDGES);
    int* rpb = rpa + (NNODES + 1);

    const int gE = (NEDGES + 255) / 256;      // 1954
    const int gC = NNODES * HID / 4 / 256;    // 6250
    const int gW = (6 * 16384 + 48 * 128 + 255) / 256;   // 408
    const int gG = (NNODES + 63) / 64;        // 782
    const int gS2 = 2 * NNODES * 64 / 256;    // 25000

    prep_all_kernel<<<4 * gE + gC + gW, 256, 0, stream>>>(
        arow, acol, aval, brow, bcol, bval, id, (const float4*)x0, mixr,
        Wl, Wr, Wout, rpa, rpb, cvA, cvB, (uint2*)x0h, (uint2*)xmh, Wt, WoT, gE, gC);

    // ---- layer 0 (aggr source = x0)
    spmm2_kernel<<<gS2, 256, 0, stream>>>(x0h, cvA, rpa, Sh, cvB, rpb, Th);
    fused_layer_kernel<true><<<gG, 256, 0, stream>>>(
        Sh, Th, xmh, x0h, Wt + 0 * 16384, Wt + 3 * 16384, bs, mixr,
        h1, nullptr, nullptr, nullptr);

    // ---- layer 1 (aggr source = h1)
    spmm2_kernel<<<gS2, 256, 0, stream>>>(h1, cvA, rpa, Sh, cvB, rpb, Th);
    fused_layer_kernel<true><<<gG, 256, 0, stream>>>(
        Sh, Th, xmh, h1, Wt + 1 * 16384, Wt + 4 * 16384, bs + 128, mixr,
        h2, nullptr, nullptr, nullptr);

    // ---- layer 2 (+ head, aggr source = h2)
    spmm2_kernel<<<gS2, 256, 0, stream>>>(h2, cvA, rpa, Sh, cvB, rpb, Th);
    fused_layer_kernel<false><<<gG, 256, 0, stream>>>(
        Sh, Th, xmh, nullptr, Wt + 2 * 16384, Wt + 5 * 16384, bs + 256, mixr,
        nullptr, WoT, bout, out);
}